// Round 1
// 238.604 us; speedup vs baseline: 1.0123x; 1.0123x over previous
//
#include <hip/hip_runtime.h>

#define SEQ 2048
#define DMODEL 1024
#define NH 16
#define DH 64

typedef __attribute__((ext_vector_type(8))) short bf16x8;
typedef __attribute__((ext_vector_type(4))) short bf16x4;
typedef __attribute__((ext_vector_type(4))) float floatx4;
typedef __attribute__((ext_vector_type(4))) unsigned short u16x4;
typedef unsigned short u16;
typedef unsigned int u32;

typedef const void __attribute__((address_space(1)))* as1cvp;
typedef void __attribute__((address_space(3)))* as3vp;

__device__ __forceinline__ void glds16(const void* g, void* l) {
    __builtin_amdgcn_global_load_lds((as1cvp)g, (as3vp)l, 16, 0, 0);
}

// f32->bf16 round-half-up: u + 0x8000, take hi16. Same 0.5-ulp worst case as
// RNE (only exact-tie direction differs -> unbiased for continuous data).
// NOT the same as v_cvt_pk_bf16_f32 truncation (-0.5 ulp BIAS, 33x absmax
// degradation measured previously). 1 VALU op per value vs ~4 for soft-RNE.
__device__ __forceinline__ u16 f2bf(float f) {
    union { u32 u; float f; } v; v.f = f;
    return (u16)((v.u + 0x8000u) >> 16);
}

// packed f32->2xbf16 half-up: 2 adds + 1 v_perm_b32 (hi16 of each)
__device__ __forceinline__ u32 pk2(float a, float b) {
    union { u32 u; float f; } x, y; x.f = a; y.f = b;
    u32 xr = x.u + 0x8000u, yr = y.u + 0x8000u;
#if __has_builtin(__builtin_amdgcn_perm)
    return __builtin_amdgcn_perm(yr, xr, 0x07060302u);
#else
    return (xr >> 16) | (yr & 0xffff0000u);
#endif
}

// raw v_exp_f32 (= exp2). exp2f() library call is the slow OCML path (r5
// regression); __expf costs an extra v_mul for the log2e fold. We fold log2e
// into QSCALE instead, so scores live in the log2 domain.
__device__ __forceinline__ float ex2(float x) {
#if __has_builtin(__builtin_amdgcn_exp2f)
    return __builtin_amdgcn_exp2f(x);
#else
    float r; asm("v_exp_f32 %0, %1" : "=v"(r) : "v"(x)); return r;
#endif
}

// 16x16x16 bf16 MFMA: B-frag layout k=quad*4+j matches C-layout of S^T
__device__ __forceinline__ floatx4 mfma16(bf16x4 a, bf16x4 b, floatx4 c) {
#if __has_builtin(__builtin_amdgcn_mfma_f32_16x16x16bf16_1k)
    return __builtin_amdgcn_mfma_f32_16x16x16bf16_1k(a, b, c, 0, 0, 0);
#else
    asm volatile("v_mfma_f32_16x16x16_bf16 %0, %1, %2, %0" : "+v"(c) : "v"(a), "v"(b));
    return c;
#endif
}

__device__ __forceinline__ uint4 cvt8(const float* __restrict__ p) {
    float4 a = *(const float4*)p;
    float4 b = *(const float4*)(p + 4);
    uint4 q;
    q.x = pk2(a.x, a.y); q.y = pk2(a.z, a.w);
    q.z = pk2(b.x, b.y); q.w = pk2(b.z, b.w);
    return q;
}

// q pre-scale: 1/sqrt(Dh) * log2(e) -> scores are log2-domain, exp via v_exp_f32
#define QSCALE 0.18033688011112042f

// ---------------- convert Q,K,V + 4 weights to bf16 once ----------------
__global__ __launch_bounds__(256) void cvt_all(
    const float* __restrict__ Q, const float* __restrict__ K, const float* __restrict__ V,
    const float* __restrict__ W0, const float* __restrict__ W1,
    const float* __restrict__ W2, const float* __restrict__ W3,
    u16* __restrict__ Qb, u16* __restrict__ Kb, u16* __restrict__ Vb,
    u16* __restrict__ Wb)
{
    const int y = blockIdx.y;
    const float* src; u16* dst;
    if (y == 0)      { src = Q;  dst = Qb; }
    else if (y == 1) { src = K;  dst = Kb; }
    else if (y == 2) { src = V;  dst = Vb; }
    else {
        if (blockIdx.x >= 512) return;
        src = (y == 3) ? W0 : (y == 4) ? W1 : (y == 5) ? W2 : W3;
        dst = Wb + (size_t)(y - 3) * 1048576;
    }
    size_t i = ((size_t)blockIdx.x * 256 + threadIdx.x) * 8;
    *(uint4*)(dst + i) = cvt8(src + i);
}

__global__ __launch_bounds__(256) void cvt_w(
    const float* __restrict__ W0, const float* __restrict__ W1,
    const float* __restrict__ W2, const float* __restrict__ W3,
    u16* __restrict__ out)
{
    const float* src = (blockIdx.y == 0) ? W0 : (blockIdx.y == 1) ? W1
                     : (blockIdx.y == 2) ? W2 : W3;
    size_t i = ((size_t)blockIdx.x * 256 + threadIdx.x) * 8;
    *(uint4*)(out + (size_t)blockIdx.y * 1048576 + i) = cvt8(src + i);
}

// shared epilogue store for QKV projections (z<2: scalar, z=2: vectorized 8B)
__device__ __forceinline__ void qkv_store(
    int z, u16* __restrict__ outp, int rowg, int col, floatx4 a4, float bv, float sc)
{
    union { u32 w[2]; u16 h[4]; u16x4 v4; } pk;
    pk.w[0] = pk2((a4[0] + bv) * sc, (a4[1] + bv) * sc);
    pk.w[1] = pk2((a4[2] + bv) * sc, (a4[3] + bv) * sc);
    int b = rowg >> 11, s = rowg & 2047, h = col >> 6, d = col & 63;
    if (z < 2) {
#pragma unroll
        for (int r = 0; r < 4; r++)
            outp[((size_t)(b * NH + h) * SEQ + s + r) * DH + d] = pk.h[r];
    } else {
        *(u16x4*)(outp + ((size_t)(b * NH + h) * DH + d) * SEQ + s) = pk.v4;
    }
}

// ---------------- QKV projection, both operands bf16, pure glds16 staging ----------------
__global__ __launch_bounds__(256) void gemm_qkv_bb(
    const u16* __restrict__ Qb, const u16* __restrict__ Kb, const u16* __restrict__ Vb,
    const u16* __restrict__ Wb,
    const float* __restrict__ b0, const float* __restrict__ b1, const float* __restrict__ b2,
    u16* __restrict__ qo, u16* __restrict__ ko, u16* __restrict__ vto)
{
    __shared__ __align__(16) u16 As[128 * 32];
    __shared__ __align__(16) u16 Bs[128 * 32];
    const int tid = threadIdx.x, l = tid & 63, w = tid >> 6;
    const int lm = l & 15, quad = l >> 4;
    const int wr = (w >> 1) * 64, wc = (w & 1) * 64;
    const int bm = blockIdx.y * 128, bn = blockIdx.x * 128;
    const int z = blockIdx.z;
    const u16* A      = (z == 0) ? Qb : (z == 1) ? Kb : Vb;
    const u16* W      = Wb + (size_t)z * 1048576;
    const float* bias = (z == 0) ? b0 : (z == 1) ? b1 : b2;

    const int srow = tid >> 2, scol = (tid & 3) * 8;

    floatx4 acc[4][4];
#pragma unroll
    for (int i = 0; i < 4; i++)
#pragma unroll
        for (int j = 0; j < 4; j++) acc[i][j] = (floatx4){0.f, 0.f, 0.f, 0.f};

    for (int kt = 0; kt < DMODEL; kt += 32) {
        __syncthreads();
        glds16(A + (size_t)(bm + srow) * DMODEL + kt + scol, As + w * 512);
        glds16(A + (size_t)(bm + 64 + srow) * DMODEL + kt + scol, As + 2048 + w * 512);
        glds16(W + (size_t)(bn + srow) * DMODEL + kt + scol, Bs + w * 512);
        glds16(W + (size_t)(bn + 64 + srow) * DMODEL + kt + scol, Bs + 2048 + w * 512);
        __syncthreads();

        bf16x8 af[4], bfr[4];
#pragma unroll
        for (int mi = 0; mi < 4; mi++)
            af[mi] = *(const bf16x8*)(As + (wr + mi * 16 + lm) * 32 + quad * 8);
#pragma unroll
        for (int ni = 0; ni < 4; ni++)
            bfr[ni] = *(const bf16x8*)(Bs + (wc + ni * 16 + lm) * 32 + quad * 8);
#pragma unroll
        for (int mi = 0; mi < 4; mi++)
#pragma unroll
            for (int ni = 0; ni < 4; ni++)
                acc[mi][ni] = __builtin_amdgcn_mfma_f32_16x16x32_bf16(
                    af[mi], bfr[ni], acc[mi][ni], 0, 0, 0);
    }

    const float sc = (z == 0) ? QSCALE : 1.0f;
    u16* outp = (z == 0) ? qo : (z == 1) ? ko : vto;
#pragma unroll
    for (int ni = 0; ni < 4; ni++) {
        int col = bn + wc + ni * 16 + lm;
        float bv = bias[col];
#pragma unroll
        for (int mi = 0; mi < 4; mi++)
            qkv_store(z, outp, bm + wr + mi * 16 + quad * 4, col, acc[mi][ni], bv, sc);
    }
}

// ---------------- legacy QKV (A f32 converted in staging) ----------------
template<bool WBF>
__global__ __launch_bounds__(256) void gemm_qkv(
    const float* __restrict__ Qf, const float* __restrict__ Kf, const float* __restrict__ Vf,
    const void* __restrict__ W0, const void* __restrict__ W1, const void* __restrict__ W2,
    const float* __restrict__ b0, const float* __restrict__ b1, const float* __restrict__ b2,
    u16* __restrict__ qo, u16* __restrict__ ko, u16* __restrict__ vto)
{
    __shared__ __align__(16) u16 As[128 * 32];
    __shared__ __align__(16) u16 Bs[128 * 32];
    const int tid = threadIdx.x, l = tid & 63, w = tid >> 6;
    const int lm = l & 15, quad = l >> 4;
    const int wr = (w >> 1) * 64, wc = (w & 1) * 64;
    const int bm = blockIdx.y * 128, bn = blockIdx.x * 128;
    const int z = blockIdx.z;
    const float* A    = (z == 0) ? Qf : (z == 1) ? Kf : Vf;
    const void* Wp    = (z == 0) ? W0 : (z == 1) ? W1 : W2;
    const float* bias = (z == 0) ? b0 : (z == 1) ? b1 : b2;

    floatx4 acc[4][4];
#pragma unroll
    for (int i = 0; i < 4; i++)
#pragma unroll
        for (int j = 0; j < 4; j++) acc[i][j] = (floatx4){0.f, 0.f, 0.f, 0.f};

    for (int kt = 0; kt < DMODEL; kt += 32) {
        __syncthreads();
#pragma unroll
        for (int j = 0; j < 2; j++) {
            int ch = j * 256 + tid, row = ch >> 2, c = ch & 3;
            *(uint4*)(As + ch * 8) = cvt8(A + (size_t)(bm + row) * DMODEL + kt + c * 8);
        }
        if (WBF) {
            const u16* Wb = (const u16*)Wp;
            glds16(Wb + (size_t)(bn + (tid >> 2)) * DMODEL + kt + (tid & 3) * 8, Bs + w * 512);
            glds16(Wb + (size_t)(bn + 64 + (tid >> 2)) * DMODEL + kt + (tid & 3) * 8, Bs + 2048 + w * 512);
        } else {
            const float* Wf = (const float*)Wp;
#pragma unroll
            for (int j = 0; j < 2; j++) {
                int ch = j * 256 + tid, row = ch >> 2, c = ch & 3;
                *(uint4*)(Bs + ch * 8) = cvt8(Wf + (size_t)(bn + row) * DMODEL + kt + c * 8);
            }
        }
        __syncthreads();

        bf16x8 af[4], bfr[4];
#pragma unroll
        for (int mi = 0; mi < 4; mi++)
            af[mi] = *(const bf16x8*)(As + (wr + mi * 16 + lm) * 32 + quad * 8);
#pragma unroll
        for (int ni = 0; ni < 4; ni++)
            bfr[ni] = *(const bf16x8*)(Bs + (wc + ni * 16 + lm) * 32 + quad * 8);
#pragma unroll
        for (int mi = 0; mi < 4; mi++)
#pragma unroll
            for (int ni = 0; ni < 4; ni++)
                acc[mi][ni] = __builtin_amdgcn_mfma_f32_16x16x32_bf16(
                    af[mi], bfr[ni], acc[mi][ni], 0, 0, 0);
    }

    const float sc = (z == 0) ? QSCALE : 1.0f;
    u16* outp = (z == 0) ? qo : (z == 1) ? ko : vto;
#pragma unroll
    for (int ni = 0; ni < 4; ni++) {
        int col = bn + wc + ni * 16 + lm;
        float bv = bias[col];
#pragma unroll
        for (int mi = 0; mi < 4; mi++)
            qkv_store(z, outp, bm + wr + mi * 16 + quad * 4, col, acc[mi][ni], bv, sc);
    }
}

// ---------------- O-projection: A bf16, W bf16/f32, out f32. 128x64 tiles ----------------
template<bool WBF>
__global__ __launch_bounds__(256) void gemm_o(
    const u16* __restrict__ A, const void* __restrict__ Wp,
    const float* __restrict__ bias, float* __restrict__ out)
{
    __shared__ __align__(16) u16 As[128 * 32];
    __shared__ __align__(16) u16 Bs[64 * 32];
    const int tid = threadIdx.x, l = tid & 63, w = tid >> 6;
    const int lm = l & 15, quad = l >> 4;
    const int bm = blockIdx.y * 128, bn = blockIdx.x * 64;

    floatx4 acc[2][4];
#pragma unroll
    for (int i = 0; i < 2; i++)
#pragma unroll
        for (int j = 0; j < 4; j++) acc[i][j] = (floatx4){0.f, 0.f, 0.f, 0.f};

    for (int kt = 0; kt < DMODEL; kt += 32) {
        __syncthreads();
        glds16(A + (size_t)(bm + (tid >> 2)) * DMODEL + kt + (tid & 3) * 8, As + w * 512);
        glds16(A + (size_t)(bm + 64 + (tid >> 2)) * DMODEL + kt + (tid & 3) * 8, As + 2048 + w * 512);
        if (WBF) {
            glds16((const u16*)Wp + (size_t)(bn + (tid >> 2)) * DMODEL + kt + (tid & 3) * 8, Bs + w * 512);
        } else {
            *(uint4*)(Bs + tid * 8) =
                cvt8((const float*)Wp + (size_t)(bn + (tid >> 2)) * DMODEL + kt + (tid & 3) * 8);
        }
        __syncthreads();

        bf16x8 af[2], bfr[4];
#pragma unroll
        for (int mi = 0; mi < 2; mi++)
            af[mi] = *(const bf16x8*)(As + (w * 32 + mi * 16 + lm) * 32 + quad * 8);
#pragma unroll
        for (int ni = 0; ni < 4; ni++)
            bfr[ni] = *(const bf16x8*)(Bs + (ni * 16 + lm) * 32 + quad * 8);
#pragma unroll
        for (int mi = 0; mi < 2; mi++)
#pragma unroll
            for (int ni = 0; ni < 4; ni++)
                acc[mi][ni] = __builtin_amdgcn_mfma_f32_16x16x32_bf16(
                    af[mi], bfr[ni], acc[mi][ni], 0, 0, 0);
    }

#pragma unroll
    for (int ni = 0; ni < 4; ni++) {
        int col = bn + ni * 16 + lm;
        float bv = bias[col];
#pragma unroll
        for (int mi = 0; mi < 2; mi++) {
#pragma unroll
            for (int r = 0; r < 4; r++) {
                int rowg = bm + w * 32 + mi * 16 + quad * 4 + r;
                out[(size_t)rowg * DMODEL + col] = acc[mi][ni][r] + bv;
            }
        }
    }
}

// ---------------- Flash attention v6: S^T formulation, log2-domain softmax ----------------
// grid (SEQ/128, B*NH), 4 waves; wave w owns q-rows w*32..w*32+31 (2 n-tiles).
// S^T = K·Q^T -> C: col=lane&15=qrow, row=quad*4+r=key; softmax rows per-lane.
// Scores are pre-scaled by log2(e) (QSCALE) so exp = raw v_exp_f32.
// Defer-max (THR=8, log2 units): skip O-rescale while max grows < 8 -> P<=256,
// f32 l/O accumulators absorb it; wave-uniform branch via __all.
// Vs stores keys PERMUTED: key m=mt*16+q*4+j at pos q*16+mt*4+j, so a lane's PV
// A-frags for all 4 mt are 16 contiguous u16 -> 2 x ds_read_b128 per dt.
#define SP 72
__global__ __launch_bounds__(256, 2) void attn_kernel(
    const u16* __restrict__ q, const u16* __restrict__ k,
    const u16* __restrict__ vt, u16* __restrict__ out)
{
    __shared__ __align__(16) u16 Ks[64 * SP];   // [key][d]
    __shared__ __align__(16) u16 Vs[64 * SP];   // [d][key-permuted]
    const int tid = threadIdx.x, l = tid & 63, w = tid >> 6;
    const int lm = l & 15, quad = l >> 4;
    const int qt = blockIdx.x, bh = blockIdx.y;
    const int b = bh >> 4, h = bh & 15;

    bf16x8 qf[2][2];
#pragma unroll
    for (int nt = 0; nt < 2; nt++) {
        int row = qt * 128 + w * 32 + nt * 16 + lm;
        const u16* qp = q + ((size_t)bh * SEQ + row) * DH;
#pragma unroll
        for (int ks = 0; ks < 2; ks++)
            qf[nt][ks] = *(const bf16x8*)(qp + ks * 32 + quad * 8);
    }

    floatx4 O[4][2];
#pragma unroll
    for (int dt = 0; dt < 4; dt++)
#pragma unroll
        for (int nt = 0; nt < 2; nt++) O[dt][nt] = (floatx4){0.f, 0.f, 0.f, 0.f};
    float mrun[2] = {-1e30f, -1e30f}, lrun[2] = {0.f, 0.f};

    const int srow = tid >> 3, scol = (tid & 7) * 8;
    // permuted V position base: chunk scol..scol+3 -> pb0, scol+4..scol+7 -> pb0+16
    const int pb0 = ((scol >> 2) & 3) * 16 + (scol >> 4) * 4;
    const u16* kbase = k + (size_t)bh * SEQ * DH;
    const u16* vbase = vt + (size_t)bh * DH * SEQ;
    uint4 kr0, kr1, vr0, vr1;
    kr0 = *(const uint4*)(kbase + (size_t)srow * DH + scol);
    kr1 = *(const uint4*)(kbase + (size_t)(srow + 32) * DH + scol);
    vr0 = *(const uint4*)(vbase + (size_t)srow * SEQ + scol);
    vr1 = *(const uint4*)(vbase + (size_t)(srow + 32) * SEQ + scol);

    for (int t = 0; t < SEQ / 64; t++) {
        __syncthreads();
        *(uint4*)(Ks + srow * SP + scol) = kr0;
        *(uint4*)(Ks + (srow + 32) * SP + scol) = kr1;
        *(uint2*)(Vs + srow * SP + pb0)             = make_uint2(vr0.x, vr0.y);
        *(uint2*)(Vs + srow * SP + pb0 + 16)        = make_uint2(vr0.z, vr0.w);
        *(uint2*)(Vs + (srow + 32) * SP + pb0)      = make_uint2(vr1.x, vr1.y);
        *(uint2*)(Vs + (srow + 32) * SP + pb0 + 16) = make_uint2(vr1.z, vr1.w);
        __syncthreads();
        if (t + 1 < SEQ / 64) {
            const u16* kg = kbase + (size_t)(t + 1) * 64 * DH;
            const u16* vg = vbase + (size_t)(t + 1) * 64;
            kr0 = *(const uint4*)(kg + (size_t)srow * DH + scol);
            kr1 = *(const uint4*)(kg + (size_t)(srow + 32) * DH + scol);
            vr0 = *(const uint4*)(vg + (size_t)srow * SEQ + scol);
            vr1 = *(const uint4*)(vg + (size_t)(srow + 32) * SEQ + scol);
        }

        // S^T = K·Q^T
        floatx4 Sc[4][2];
#pragma unroll
        for (int mt = 0; mt < 4; mt++) {
            bf16x8 ka0 = *(const bf16x8*)(Ks + (mt * 16 + lm) * SP + quad * 8);
            bf16x8 ka1 = *(const bf16x8*)(Ks + (mt * 16 + lm) * SP + 32 + quad * 8);
#pragma unroll
            for (int nt = 0; nt < 2; nt++) {
                floatx4 c = (floatx4){0.f, 0.f, 0.f, 0.f};
                c = __builtin_amdgcn_mfma_f32_16x16x32_bf16(ka0, qf[nt][0], c, 0, 0, 0);
                c = __builtin_amdgcn_mfma_f32_16x16x32_bf16(ka1, qf[nt][1], c, 0, 0, 0);
                Sc[mt][nt] = c;
            }
        }

        // online softmax: per-lane rows, 2 shuffles per reduction, log2 domain
        bf16x4 pb[4][2];
#pragma unroll
        for (int nt = 0; nt < 2; nt++) {
            float m0 = -1e30f;
#pragma unroll
            for (int mt = 0; mt < 4; mt++)
#pragma unroll
                for (int r = 0; r < 4; r++) m0 = fmaxf(m0, Sc[mt][nt][r]);
            m0 = fmaxf(m0, __shfl_xor(m0, 16));
            m0 = fmaxf(m0, __shfl_xor(m0, 32));
            // defer-max (T13): only rescale when the max grew by >= 8 (P<=2^8)
            if (!__all(m0 <= mrun[nt] + 8.0f)) {
                float mn = fmaxf(mrun[nt], m0);
                float alpha = ex2(mrun[nt] - mn);
                mrun[nt] = mn;
                lrun[nt] *= alpha;
#pragma unroll
                for (int dt = 0; dt < 4; dt++)
#pragma unroll
                    for (int r = 0; r < 4; r++) O[dt][nt][r] *= alpha;
            }
            const float mn = mrun[nt];
            float s0 = 0.f;
#pragma unroll
            for (int mt = 0; mt < 4; mt++) {
#pragma unroll
                for (int r = 0; r < 4; r++) {
                    float e = ex2(Sc[mt][nt][r] - mn);
                    Sc[mt][nt][r] = e;
                    s0 += e;
                }
                union { u32 w2[2]; bf16x4 v; } pku;
                pku.w2[0] = pk2(Sc[mt][nt][0], Sc[mt][nt][1]);
                pku.w2[1] = pk2(Sc[mt][nt][2], Sc[mt][nt][3]);
                pb[mt][nt] = pku.v;
            }
            s0 += __shfl_xor(s0, 16);
            s0 += __shfl_xor(s0, 32);
            lrun[nt] += s0;
        }

        // O^T += V^T·P^T : permuted Vs -> 2 b128 reads per dt cover all 4 mt frags
#pragma unroll
        for (int dt = 0; dt < 4; dt++) {
            const u16* vp = Vs + (dt * 16 + lm) * SP + quad * 16;
            bf16x8 v8a = *(const bf16x8*)vp;        // mt 0 (elems 0-3), mt 1 (4-7)
            bf16x8 v8b = *(const bf16x8*)(vp + 8);  // mt 2, mt 3
            bf16x4 va0 = __builtin_shufflevector(v8a, v8a, 0, 1, 2, 3);
            bf16x4 va1 = __builtin_shufflevector(v8a, v8a, 4, 5, 6, 7);
            bf16x4 va2 = __builtin_shufflevector(v8b, v8b, 0, 1, 2, 3);
            bf16x4 va3 = __builtin_shufflevector(v8b, v8b, 4, 5, 6, 7);
            O[dt][0] = mfma16(va0, pb[0][0], O[dt][0]);
            O[dt][1] = mfma16(va0, pb[0][1], O[dt][1]);
            O[dt][0] = mfma16(va1, pb[1][0], O[dt][0]);
            O[dt][1] = mfma16(va1, pb[1][1], O[dt][1]);
            O[dt][0] = mfma16(va2, pb[2][0], O[dt][0]);
            O[dt][1] = mfma16(va2, pb[2][1], O[dt][1]);
            O[dt][0] = mfma16(va3, pb[3][0], O[dt][0]);
            O[dt][1] = mfma16(va3, pb[3][1], O[dt][1]);
        }
    }

    // epilogue: O^T C-layout -> out[B,S,D]: lane writes 4 consecutive d (8B)
#pragma unroll
    for (int nt = 0; nt < 2; nt++) {
        float inv = 1.0f / lrun[nt];
        int s = qt * 128 + w * 32 + nt * 16 + lm;
        u16* op = out + ((size_t)b * SEQ + s) * DMODEL + h * DH;
#pragma unroll
        for (int dt = 0; dt < 4; dt++) {
            union { u32 w2[2]; u16x4 v; } pku;
            pku.w2[0] = pk2(O[dt][nt][0] * inv, O[dt][nt][1] * inv);
            pku.w2[1] = pk2(O[dt][nt][2] * inv, O[dt][nt][3] * inv);
            *(u16x4*)(op + dt * 16 + quad * 4) = pku.v;
        }
    }
}

extern "C" void kernel_launch(void* const* d_in, const int* in_sizes, int n_in,
                              void* d_out, int out_size, void* d_ws, size_t ws_size,
                              hipStream_t stream) {
    (void)in_sizes; (void)n_in; (void)out_size;
    const float* Q  = (const float*)d_in[0];
    const float* K  = (const float*)d_in[1];
    const float* V  = (const float*)d_in[2];
    const float* Wq = (const float*)d_in[3];
    const float* bq = (const float*)d_in[4];
    const float* Wk = (const float*)d_in[5];
    const float* bk = (const float*)d_in[6];
    const float* Wv = (const float*)d_in[7];
    const float* bv = (const float*)d_in[8];
    const float* Wo = (const float*)d_in[9];
    const float* bo = (const float*)d_in[10];

    const size_t NEL = (size_t)2 * NH * SEQ * DH;  // 4,194,304 elements
    u16* base = (u16*)d_ws;
    dim3 bb(256);

    if (ws_size >= 8 * NEL * 2) {
        u16* Qb   = base;
        u16* Kb   = Qb + NEL;
        u16* Vb   = Kb + NEL;
        u16* Wb   = Vb + NEL;
        u16* qws  = Wb + NEL;
        u16* kws  = qws + NEL;
        u16* vtws = kws + NEL;
        u16* aws  = vtws + NEL;
        cvt_all<<<dim3(2048, 7), bb, 0, stream>>>(Q, K, V, Wq, Wk, Wv, Wo, Qb, Kb, Vb, Wb);
        gemm_qkv_bb<<<dim3(8, 32, 3), bb, 0, stream>>>(
            Qb, Kb, Vb, Wb, bq, bk, bv, qws, kws, vtws);
        attn_kernel<<<dim3(SEQ / 128, 2 * NH), bb, 0, stream>>>(qws, kws, vtws, aws);
        gemm_o<true><<<dim3(16, 32), bb, 0, stream>>>(aws, Wb + 3145728, bo, (float*)d_out);
    } else if (ws_size >= 5 * NEL * 2) {
        u16* Wb = base;
        u16* qws = base + NEL; u16* kws = qws + NEL; u16* vtws = kws + NEL; u16* aws = vtws + NEL;
        cvt_w<<<dim3(512, 4), bb, 0, stream>>>(Wq, Wk, Wv, Wo, Wb);
        gemm_qkv<true><<<dim3(8, 32, 3), bb, 0, stream>>>(
            Q, K, V, Wb, Wb + 1048576, Wb + 2097152, bq, bk, bv, qws, kws, vtws);
        attn_kernel<<<dim3(SEQ / 128, 2 * NH), bb, 0, stream>>>(qws, kws, vtws, aws);
        gemm_o<true><<<dim3(16, 32), bb, 0, stream>>>(aws, Wb + 3145728, bo, (float*)d_out);
    } else {
        u16* qws = base; u16* kws = qws + NEL; u16* vtws = kws + NEL; u16* aws = vtws + NEL;
        gemm_qkv<false><<<dim3(8, 32, 3), bb, 0, stream>>>(
            Q, K, V, Wq, Wk, Wv, bq, bk, bv, qws, kws, vtws);
        attn_kernel<<<dim3(SEQ / 128, 2 * NH), bb, 0, stream>>>(qws, kws, vtws, aws);
        gemm_o<false><<<dim3(16, 32), bb, 0, stream>>>(aws, Wo, bo, (float*)d_out);
    }
}

// Round 2
// 231.885 us; speedup vs baseline: 1.0417x; 1.0290x over previous
//
#include <hip/hip_runtime.h>

#define SEQ 2048
#define DMODEL 1024
#define NH 16
#define DH 64

typedef __attribute__((ext_vector_type(8))) short bf16x8;
typedef __attribute__((ext_vector_type(4))) short bf16x4;
typedef __attribute__((ext_vector_type(4))) float floatx4;
typedef __attribute__((ext_vector_type(4))) unsigned short u16x4;
typedef unsigned short u16;
typedef unsigned int u32;

typedef const void __attribute__((address_space(1)))* as1cvp;
typedef void __attribute__((address_space(3)))* as3vp;

__device__ __forceinline__ void glds16(const void* g, void* l) {
    __builtin_amdgcn_global_load_lds((as1cvp)g, (as3vp)l, 16, 0, 0);
}

// f32->bf16 round-half-up: u + 0x8000, take hi16. Same 0.5-ulp worst case as
// RNE (only exact-tie direction differs -> unbiased for continuous data).
__device__ __forceinline__ u16 f2bf(float f) {
    union { u32 u; float f; } v; v.f = f;
    return (u16)((v.u + 0x8000u) >> 16);
}

// packed f32->2xbf16 half-up: 2 adds + 1 v_perm_b32 (hi16 of each)
__device__ __forceinline__ u32 pk2(float a, float b) {
    union { u32 u; float f; } x, y; x.f = a; y.f = b;
    u32 xr = x.u + 0x8000u, yr = y.u + 0x8000u;
#if __has_builtin(__builtin_amdgcn_perm)
    return __builtin_amdgcn_perm(yr, xr, 0x07060302u);
#else
    return (xr >> 16) | (yr & 0xffff0000u);
#endif
}

// raw v_exp_f32 (= exp2); log2e folded into QSCALE so scores are log2-domain.
__device__ __forceinline__ float ex2(float x) {
#if __has_builtin(__builtin_amdgcn_exp2f)
    return __builtin_amdgcn_exp2f(x);
#else
    float r; asm("v_exp_f32 %0, %1" : "=v"(r) : "v"(x)); return r;
#endif
}

__device__ __forceinline__ float max3f(float a, float b, float c) {
    return fmaxf(fmaxf(a, b), c);   // clang fuses to v_max3_f32
}

// 16x16x16 bf16 MFMA: B-frag layout k=quad*4+j matches C-layout of S^T
__device__ __forceinline__ floatx4 mfma16(bf16x4 a, bf16x4 b, floatx4 c) {
#if __has_builtin(__builtin_amdgcn_mfma_f32_16x16x16bf16_1k)
    return __builtin_amdgcn_mfma_f32_16x16x16bf16_1k(a, b, c, 0, 0, 0);
#else
    asm volatile("v_mfma_f32_16x16x16_bf16 %0, %1, %2, %0" : "+v"(c) : "v"(a), "v"(b));
    return c;
#endif
}

__device__ __forceinline__ uint4 cvt8(const float* __restrict__ p) {
    float4 a = *(const float4*)p;
    float4 b = *(const float4*)(p + 4);
    uint4 q;
    q.x = pk2(a.x, a.y); q.y = pk2(a.z, a.w);
    q.z = pk2(b.x, b.y); q.w = pk2(b.z, b.w);
    return q;
}

// q pre-scale: 1/sqrt(Dh) * log2(e) -> scores are log2-domain, exp via v_exp_f32
#define QSCALE 0.18033688011112042f

// ---------------- convert Q,K,V + 4 weights to bf16 once ----------------
__global__ __launch_bounds__(256) void cvt_all(
    const float* __restrict__ Q, const float* __restrict__ K, const float* __restrict__ V,
    const float* __restrict__ W0, const float* __restrict__ W1,
    const float* __restrict__ W2, const float* __restrict__ W3,
    u16* __restrict__ Qb, u16* __restrict__ Kb, u16* __restrict__ Vb,
    u16* __restrict__ Wb)
{
    const int y = blockIdx.y;
    const float* src; u16* dst;
    if (y == 0)      { src = Q;  dst = Qb; }
    else if (y == 1) { src = K;  dst = Kb; }
    else if (y == 2) { src = V;  dst = Vb; }
    else {
        if (blockIdx.x >= 512) return;
        src = (y == 3) ? W0 : (y == 4) ? W1 : (y == 5) ? W2 : W3;
        dst = Wb + (size_t)(y - 3) * 1048576;
    }
    size_t i = ((size_t)blockIdx.x * 256 + threadIdx.x) * 8;
    *(uint4*)(dst + i) = cvt8(src + i);
}

__global__ __launch_bounds__(256) void cvt_w(
    const float* __restrict__ W0, const float* __restrict__ W1,
    const float* __restrict__ W2, const float* __restrict__ W3,
    u16* __restrict__ out)
{
    const float* src = (blockIdx.y == 0) ? W0 : (blockIdx.y == 1) ? W1
                     : (blockIdx.y == 2) ? W2 : W3;
    size_t i = ((size_t)blockIdx.x * 256 + threadIdx.x) * 8;
    *(uint4*)(out + (size_t)blockIdx.y * 1048576 + i) = cvt8(src + i);
}

// shared epilogue store for QKV projections (z<2: scalar, z=2: vectorized 8B)
__device__ __forceinline__ void qkv_store(
    int z, u16* __restrict__ outp, int rowg, int col, floatx4 a4, float bv, float sc)
{
    union { u32 w[2]; u16 h[4]; u16x4 v4; } pk;
    pk.w[0] = pk2((a4[0] + bv) * sc, (a4[1] + bv) * sc);
    pk.w[1] = pk2((a4[2] + bv) * sc, (a4[3] + bv) * sc);
    int b = rowg >> 11, s = rowg & 2047, h = col >> 6, d = col & 63;
    if (z < 2) {
#pragma unroll
        for (int r = 0; r < 4; r++)
            outp[((size_t)(b * NH + h) * SEQ + s + r) * DH + d] = pk.h[r];
    } else {
        *(u16x4*)(outp + ((size_t)(b * NH + h) * DH + d) * SEQ + s) = pk.v4;
    }
}

// ---------------- QKV projection, both operands bf16, pure glds16 staging ----------------
__global__ __launch_bounds__(256) void gemm_qkv_bb(
    const u16* __restrict__ Qb, const u16* __restrict__ Kb, const u16* __restrict__ Vb,
    const u16* __restrict__ Wb,
    const float* __restrict__ b0, const float* __restrict__ b1, const float* __restrict__ b2,
    u16* __restrict__ qo, u16* __restrict__ ko, u16* __restrict__ vto)
{
    __shared__ __align__(16) u16 As[128 * 32];
    __shared__ __align__(16) u16 Bs[128 * 32];
    const int tid = threadIdx.x, l = tid & 63, w = tid >> 6;
    const int lm = l & 15, quad = l >> 4;
    const int wr = (w >> 1) * 64, wc = (w & 1) * 64;
    const int bm = blockIdx.y * 128, bn = blockIdx.x * 128;
    const int z = blockIdx.z;
    const u16* A      = (z == 0) ? Qb : (z == 1) ? Kb : Vb;
    const u16* W      = Wb + (size_t)z * 1048576;
    const float* bias = (z == 0) ? b0 : (z == 1) ? b1 : b2;

    const int srow = tid >> 2, scol = (tid & 3) * 8;

    floatx4 acc[4][4];
#pragma unroll
    for (int i = 0; i < 4; i++)
#pragma unroll
        for (int j = 0; j < 4; j++) acc[i][j] = (floatx4){0.f, 0.f, 0.f, 0.f};

    for (int kt = 0; kt < DMODEL; kt += 32) {
        __syncthreads();
        glds16(A + (size_t)(bm + srow) * DMODEL + kt + scol, As + w * 512);
        glds16(A + (size_t)(bm + 64 + srow) * DMODEL + kt + scol, As + 2048 + w * 512);
        glds16(W + (size_t)(bn + srow) * DMODEL + kt + scol, Bs + w * 512);
        glds16(W + (size_t)(bn + 64 + srow) * DMODEL + kt + scol, Bs + 2048 + w * 512);
        __syncthreads();

        bf16x8 af[4], bfr[4];
#pragma unroll
        for (int mi = 0; mi < 4; mi++)
            af[mi] = *(const bf16x8*)(As + (wr + mi * 16 + lm) * 32 + quad * 8);
#pragma unroll
        for (int ni = 0; ni < 4; ni++)
            bfr[ni] = *(const bf16x8*)(Bs + (wc + ni * 16 + lm) * 32 + quad * 8);
#pragma unroll
        for (int mi = 0; mi < 4; mi++)
#pragma unroll
            for (int ni = 0; ni < 4; ni++)
                acc[mi][ni] = __builtin_amdgcn_mfma_f32_16x16x32_bf16(
                    af[mi], bfr[ni], acc[mi][ni], 0, 0, 0);
    }

    const float sc = (z == 0) ? QSCALE : 1.0f;
    u16* outp = (z == 0) ? qo : (z == 1) ? ko : vto;
#pragma unroll
    for (int ni = 0; ni < 4; ni++) {
        int col = bn + wc + ni * 16 + lm;
        float bv = bias[col];
#pragma unroll
        for (int mi = 0; mi < 4; mi++)
            qkv_store(z, outp, bm + wr + mi * 16 + quad * 4, col, acc[mi][ni], bv, sc);
    }
}

// ---------------- legacy QKV (A f32 converted in staging) ----------------
template<bool WBF>
__global__ __launch_bounds__(256) void gemm_qkv(
    const float* __restrict__ Qf, const float* __restrict__ Kf, const float* __restrict__ Vf,
    const void* __restrict__ W0, const void* __restrict__ W1, const void* __restrict__ W2,
    const float* __restrict__ b0, const float* __restrict__ b1, const float* __restrict__ b2,
    u16* __restrict__ qo, u16* __restrict__ ko, u16* __restrict__ vto)
{
    __shared__ __align__(16) u16 As[128 * 32];
    __shared__ __align__(16) u16 Bs[128 * 32];
    const int tid = threadIdx.x, l = tid & 63, w = tid >> 6;
    const int lm = l & 15, quad = l >> 4;
    const int wr = (w >> 1) * 64, wc = (w & 1) * 64;
    const int bm = blockIdx.y * 128, bn = blockIdx.x * 128;
    const int z = blockIdx.z;
    const float* A    = (z == 0) ? Qf : (z == 1) ? Kf : Vf;
    const void* Wp    = (z == 0) ? W0 : (z == 1) ? W1 : W2;
    const float* bias = (z == 0) ? b0 : (z == 1) ? b1 : b2;

    floatx4 acc[4][4];
#pragma unroll
    for (int i = 0; i < 4; i++)
#pragma unroll
        for (int j = 0; j < 4; j++) acc[i][j] = (floatx4){0.f, 0.f, 0.f, 0.f};

    for (int kt = 0; kt < DMODEL; kt += 32) {
        __syncthreads();
#pragma unroll
        for (int j = 0; j < 2; j++) {
            int ch = j * 256 + tid, row = ch >> 2, c = ch & 3;
            *(uint4*)(As + ch * 8) = cvt8(A + (size_t)(bm + row) * DMODEL + kt + c * 8);
        }
        if (WBF) {
            const u16* Wb = (const u16*)Wp;
            glds16(Wb + (size_t)(bn + (tid >> 2)) * DMODEL + kt + (tid & 3) * 8, Bs + w * 512);
            glds16(Wb + (size_t)(bn + 64 + (tid >> 2)) * DMODEL + kt + (tid & 3) * 8, Bs + 2048 + w * 512);
        } else {
            const float* Wf = (const float*)Wp;
#pragma unroll
            for (int j = 0; j < 2; j++) {
                int ch = j * 256 + tid, row = ch >> 2, c = ch & 3;
                *(uint4*)(Bs + ch * 8) = cvt8(Wf + (size_t)(bn + row) * DMODEL + kt + c * 8);
            }
        }
        __syncthreads();

        bf16x8 af[4], bfr[4];
#pragma unroll
        for (int mi = 0; mi < 4; mi++)
            af[mi] = *(const bf16x8*)(As + (wr + mi * 16 + lm) * 32 + quad * 8);
#pragma unroll
        for (int ni = 0; ni < 4; ni++)
            bfr[ni] = *(const bf16x8*)(Bs + (wc + ni * 16 + lm) * 32 + quad * 8);
#pragma unroll
        for (int mi = 0; mi < 4; mi++)
#pragma unroll
            for (int ni = 0; ni < 4; ni++)
                acc[mi][ni] = __builtin_amdgcn_mfma_f32_16x16x32_bf16(
                    af[mi], bfr[ni], acc[mi][ni], 0, 0, 0);
    }

    const float sc = (z == 0) ? QSCALE : 1.0f;
    u16* outp = (z == 0) ? qo : (z == 1) ? ko : vto;
#pragma unroll
    for (int ni = 0; ni < 4; ni++) {
        int col = bn + wc + ni * 16 + lm;
        float bv = bias[col];
#pragma unroll
        for (int mi = 0; mi < 4; mi++)
            qkv_store(z, outp, bm + wr + mi * 16 + quad * 4, col, acc[mi][ni], bv, sc);
    }
}

// ---------------- O-projection: A bf16, W bf16/f32, out f32. 128x64 tiles ----------------
template<bool WBF>
__global__ __launch_bounds__(256) void gemm_o(
    const u16* __restrict__ A, const void* __restrict__ Wp,
    const float* __restrict__ bias, float* __restrict__ out)
{
    __shared__ __align__(16) u16 As[128 * 32];
    __shared__ __align__(16) u16 Bs[64 * 32];
    const int tid = threadIdx.x, l = tid & 63, w = tid >> 6;
    const int lm = l & 15, quad = l >> 4;
    const int bm = blockIdx.y * 128, bn = blockIdx.x * 64;

    floatx4 acc[2][4];
#pragma unroll
    for (int i = 0; i < 2; i++)
#pragma unroll
        for (int j = 0; j < 4; j++) acc[i][j] = (floatx4){0.f, 0.f, 0.f, 0.f};

    for (int kt = 0; kt < DMODEL; kt += 32) {
        __syncthreads();
        glds16(A + (size_t)(bm + (tid >> 2)) * DMODEL + kt + (tid & 3) * 8, As + w * 512);
        glds16(A + (size_t)(bm + 64 + (tid >> 2)) * DMODEL + kt + (tid & 3) * 8, As + 2048 + w * 512);
        if (WBF) {
            glds16((const u16*)Wp + (size_t)(bn + (tid >> 2)) * DMODEL + kt + (tid & 3) * 8, Bs + w * 512);
        } else {
            *(uint4*)(Bs + tid * 8) =
                cvt8((const float*)Wp + (size_t)(bn + (tid >> 2)) * DMODEL + kt + (tid & 3) * 8);
        }
        __syncthreads();

        bf16x8 af[2], bfr[4];
#pragma unroll
        for (int mi = 0; mi < 2; mi++)
            af[mi] = *(const bf16x8*)(As + (w * 32 + mi * 16 + lm) * 32 + quad * 8);
#pragma unroll
        for (int ni = 0; ni < 4; ni++)
            bfr[ni] = *(const bf16x8*)(Bs + (ni * 16 + lm) * 32 + quad * 8);
#pragma unroll
        for (int mi = 0; mi < 2; mi++)
#pragma unroll
            for (int ni = 0; ni < 4; ni++)
                acc[mi][ni] = __builtin_amdgcn_mfma_f32_16x16x32_bf16(
                    af[mi], bfr[ni], acc[mi][ni], 0, 0, 0);
    }

#pragma unroll
    for (int ni = 0; ni < 4; ni++) {
        int col = bn + ni * 16 + lm;
        float bv = bias[col];
#pragma unroll
        for (int mi = 0; mi < 2; mi++) {
#pragma unroll
            for (int r = 0; r < 4; r++) {
                int rowg = bm + w * 32 + mi * 16 + quad * 4 + r;
                out[(size_t)rowg * DMODEL + col] = acc[mi][ni][r] + bv;
            }
        }
    }
}

// ---------------- Flash attention v7: 8-wave blocks, l-via-MFMA ----------------
// grid (SEQ/128, B*NH), 512 threads / 8 waves; wave w owns q-rows w*16..w*16+15.
// Occupancy: 2 blocks/CU x 8 waves = 16 waves/CU (4/SIMD) vs v6's 8/CU; K/V
// staging amortized over 8 waves (1 uint4 K + 1 uint4 V per thread per tile).
// S^T = K*Q^T -> C: col=lane&15=qrow, row=quad*4+r=key; softmax rows per-lane.
// Scores pre-scaled by log2(e) (QSCALE): exp = raw v_exp_f32; defer-max THR=8.
// l = sum(bf16(P)) folded into MFMA: all-ones A-frag -> every C element of Ol
// is the column sum for col=lm, which IS this lane's q-row -> no shuffles, and
// deferred-max rescale of l is automatic (same accumulator scaling as O).
// Vs stores keys PERMUTED: key m=mt*16+q*4+j at pos q*16+mt*4+j, so a lane's PV
// A-frags for all 4 mt are 16 contiguous u16 -> 2 x ds_read_b128 per dt.
#define SP 72
__global__ __launch_bounds__(512, 4) void attn_kernel(
    const u16* __restrict__ q, const u16* __restrict__ k,
    const u16* __restrict__ vt, u16* __restrict__ out)
{
    __shared__ __align__(16) u16 Ks[64 * SP];   // [key][d]
    __shared__ __align__(16) u16 Vs[64 * SP];   // [d][key-permuted]
    const int tid = threadIdx.x, l = tid & 63, w = tid >> 6;   // w in 0..7
    const int lm = l & 15, quad = l >> 4;
    const int qt = blockIdx.x, bh = blockIdx.y;
    const int b = bh >> 4, h = bh & 15;

    bf16x8 qf[2];
    {
        int row = qt * 128 + w * 16 + lm;
        const u16* qp = q + ((size_t)bh * SEQ + row) * DH;
        qf[0] = *(const bf16x8*)(qp + quad * 8);
        qf[1] = *(const bf16x8*)(qp + 32 + quad * 8);
    }

    floatx4 O[4];
#pragma unroll
    for (int dt = 0; dt < 4; dt++) O[dt] = (floatx4){0.f, 0.f, 0.f, 0.f};
    floatx4 Ol = (floatx4){0.f, 0.f, 0.f, 0.f};   // l accumulator (ones-row)
    float mrun = -1e30f;

    const bf16x4 onesb = {(short)0x3F80, (short)0x3F80, (short)0x3F80, (short)0x3F80};

    const int srow = tid >> 3, scol = (tid & 7) * 8;  // srow 0..63, scol 0..56
    // permuted V position base: chunk scol..scol+3 -> pb0, scol+4..scol+7 -> pb0+16
    const int pb0 = ((scol >> 2) & 3) * 16 + (scol >> 4) * 4;
    const u16* kbase = k + (size_t)bh * SEQ * DH;
    const u16* vbase = vt + (size_t)bh * DH * SEQ;
    uint4 kr = *(const uint4*)(kbase + (size_t)srow * DH + scol);
    uint4 vr = *(const uint4*)(vbase + (size_t)srow * SEQ + scol);

    for (int t = 0; t < SEQ / 64; t++) {
        __syncthreads();
        *(uint4*)(Ks + srow * SP + scol) = kr;
        *(uint2*)(Vs + srow * SP + pb0)      = make_uint2(vr.x, vr.y);
        *(uint2*)(Vs + srow * SP + pb0 + 16) = make_uint2(vr.z, vr.w);
        __syncthreads();
        if (t + 1 < SEQ / 64) {
            kr = *(const uint4*)(kbase + (size_t)(t + 1) * 64 * DH + (size_t)srow * DH + scol);
            vr = *(const uint4*)(vbase + (size_t)(t + 1) * 64 + (size_t)srow * SEQ + scol);
        }

        // S^T = K·Q^T
        floatx4 Sc[4];
#pragma unroll
        for (int mt = 0; mt < 4; mt++) {
            bf16x8 ka0 = *(const bf16x8*)(Ks + (mt * 16 + lm) * SP + quad * 8);
            bf16x8 ka1 = *(const bf16x8*)(Ks + (mt * 16 + lm) * SP + 32 + quad * 8);
            floatx4 c = (floatx4){0.f, 0.f, 0.f, 0.f};
            c = __builtin_amdgcn_mfma_f32_16x16x32_bf16(ka0, qf[0], c, 0, 0, 0);
            c = __builtin_amdgcn_mfma_f32_16x16x32_bf16(ka1, qf[1], c, 0, 0, 0);
            Sc[mt] = c;
        }

        // row max over 16 values: v_max3 tree + 2 cross-quad shuffles
        float m0 = max3f(Sc[0][0], Sc[0][1], Sc[0][2]);
        float m1 = max3f(Sc[0][3], Sc[1][0], Sc[1][1]);
        float m2 = max3f(Sc[1][2], Sc[1][3], Sc[2][0]);
        float m3 = max3f(Sc[2][1], Sc[2][2], Sc[2][3]);
        float m4 = max3f(Sc[3][0], Sc[3][1], Sc[3][2]);
        m0 = max3f(m0, m1, m2);
        m0 = max3f(m0, m3, m4);
        m0 = fmaxf(m0, Sc[3][3]);
        m0 = fmaxf(m0, __shfl_xor(m0, 16));
        m0 = fmaxf(m0, __shfl_xor(m0, 32));

        // defer-max (T13): only rescale when the max grew by >= 8 (P<=2^8)
        if (!__all(m0 <= mrun + 8.0f)) {
            float mn = fmaxf(mrun, m0);
            float alpha = ex2(mrun - mn);
            mrun = mn;
#pragma unroll
            for (int dt = 0; dt < 4; dt++)
#pragma unroll
                for (int r = 0; r < 4; r++) O[dt][r] *= alpha;
            Ol[0] *= alpha;   // only element 0 is ever read
        }

        bf16x4 pb[4];
#pragma unroll
        for (int mt = 0; mt < 4; mt++) {
#pragma unroll
            for (int r = 0; r < 4; r++) Sc[mt][r] = ex2(Sc[mt][r] - mrun);
            union { u32 w2[2]; bf16x4 v; } pku;
            pku.w2[0] = pk2(Sc[mt][0], Sc[mt][1]);
            pku.w2[1] = pk2(Sc[mt][2], Sc[mt][3]);
            pb[mt] = pku.v;
        }

        // l += colsum(P) via all-ones A-frag (replaces fadd chain + shuffles)
        Ol = mfma16(onesb, pb[0], Ol);
        Ol = mfma16(onesb, pb[1], Ol);
        Ol = mfma16(onesb, pb[2], Ol);
        Ol = mfma16(onesb, pb[3], Ol);

        // O^T += V^T·P^T : permuted Vs -> 2 b128 reads per dt cover all 4 mt frags
#pragma unroll
        for (int dt = 0; dt < 4; dt++) {
            const u16* vp = Vs + (dt * 16 + lm) * SP + quad * 16;
            bf16x8 v8a = *(const bf16x8*)vp;        // mt 0 (elems 0-3), mt 1 (4-7)
            bf16x8 v8b = *(const bf16x8*)(vp + 8);  // mt 2, mt 3
            bf16x4 va0 = __builtin_shufflevector(v8a, v8a, 0, 1, 2, 3);
            bf16x4 va1 = __builtin_shufflevector(v8a, v8a, 4, 5, 6, 7);
            bf16x4 va2 = __builtin_shufflevector(v8b, v8b, 0, 1, 2, 3);
            bf16x4 va3 = __builtin_shufflevector(v8b, v8b, 4, 5, 6, 7);
            O[dt] = mfma16(va0, pb[0], O[dt]);
            O[dt] = mfma16(va1, pb[1], O[dt]);
            O[dt] = mfma16(va2, pb[2], O[dt]);
            O[dt] = mfma16(va3, pb[3], O[dt]);
        }
    }

    // epilogue: O^T C-layout -> out[B,S,D]: lane writes 4 consecutive d (8B)
    float inv = 1.0f / Ol[0];
    int s = qt * 128 + w * 16 + lm;
    u16* op = out + ((size_t)b * SEQ + s) * DMODEL + h * DH;
#pragma unroll
    for (int dt = 0; dt < 4; dt++) {
        union { u32 w2[2]; u16x4 v; } pku;
        pku.w2[0] = pk2(O[dt][0] * inv, O[dt][1] * inv);
        pku.w2[1] = pk2(O[dt][2] * inv, O[dt][3] * inv);
        *(u16x4*)(op + dt * 16 + quad * 4) = pku.v;
    }
}

extern "C" void kernel_launch(void* const* d_in, const int* in_sizes, int n_in,
                              void* d_out, int out_size, void* d_ws, size_t ws_size,
                              hipStream_t stream) {
    (void)in_sizes; (void)n_in; (void)out_size;
    const float* Q  = (const float*)d_in[0];
    const float* K  = (const float*)d_in[1];
    const float* V  = (const float*)d_in[2];
    const float* Wq = (const float*)d_in[3];
    const float* bq = (const float*)d_in[4];
    const float* Wk = (const float*)d_in[5];
    const float* bk = (const float*)d_in[6];
    const float* Wv = (const float*)d_in[7];
    const float* bv = (const float*)d_in[8];
    const float* Wo = (const float*)d_in[9];
    const float* bo = (const float*)d_in[10];

    const size_t NEL = (size_t)2 * NH * SEQ * DH;  // 4,194,304 elements
    u16* base = (u16*)d_ws;
    dim3 bb(256);
    dim3 ab(512);

    if (ws_size >= 8 * NEL * 2) {
        u16* Qb   = base;
        u16* Kb   = Qb + NEL;
        u16* Vb   = Kb + NEL;
        u16* Wb   = Vb + NEL;
        u16* qws  = Wb + NEL;
        u16* kws  = qws + NEL;
        u16* vtws = kws + NEL;
        u16* aws  = vtws + NEL;
        cvt_all<<<dim3(2048, 7), bb, 0, stream>>>(Q, K, V, Wq, Wk, Wv, Wo, Qb, Kb, Vb, Wb);
        gemm_qkv_bb<<<dim3(8, 32, 3), bb, 0, stream>>>(
            Qb, Kb, Vb, Wb, bq, bk, bv, qws, kws, vtws);
        attn_kernel<<<dim3(SEQ / 128, 2 * NH), ab, 0, stream>>>(qws, kws, vtws, aws);
        gemm_o<true><<<dim3(16, 32), bb, 0, stream>>>(aws, Wb + 3145728, bo, (float*)d_out);
    } else if (ws_size >= 5 * NEL * 2) {
        u16* Wb = base;
        u16* qws = base + NEL; u16* kws = qws + NEL; u16* vtws = kws + NEL; u16* aws = vtws + NEL;
        cvt_w<<<dim3(512, 4), bb, 0, stream>>>(Wq, Wk, Wv, Wo, Wb);
        gemm_qkv<true><<<dim3(8, 32, 3), bb, 0, stream>>>(
            Q, K, V, Wb, Wb + 1048576, Wb + 2097152, bq, bk, bv, qws, kws, vtws);
        attn_kernel<<<dim3(SEQ / 128, 2 * NH), ab, 0, stream>>>(qws, kws, vtws, aws);
        gemm_o<true><<<dim3(16, 32), bb, 0, stream>>>(aws, Wb + 3145728, bo, (float*)d_out);
    } else {
        u16* qws = base; u16* kws = qws + NEL; u16* vtws = kws + NEL; u16* aws = vtws + NEL;
        gemm_qkv<false><<<dim3(8, 32, 3), bb, 0, stream>>>(
            Q, K, V, Wq, Wk, Wv, bq, bk, bv, qws, kws, vtws);
        attn_kernel<<<dim3(SEQ / 128, 2 * NH), ab, 0, stream>>>(qws, kws, vtws, aws);
        gemm_o<false><<<dim3(16, 32), bb, 0, stream>>>(aws, Wo, bo, (float*)d_out);
    }
}

// Round 3
// 231.569 us; speedup vs baseline: 1.0431x; 1.0014x over previous
//
#include <hip/hip_runtime.h>

#define SEQ 2048
#define DMODEL 1024
#define NH 16
#define DH 64

typedef __attribute__((ext_vector_type(8))) short bf16x8;
typedef __attribute__((ext_vector_type(4))) short bf16x4;
typedef __attribute__((ext_vector_type(4))) float floatx4;
typedef __attribute__((ext_vector_type(4))) unsigned short u16x4;
typedef unsigned short u16;
typedef unsigned int u32;

typedef const void __attribute__((address_space(1)))* as1cvp;
typedef void __attribute__((address_space(3)))* as3vp;

__device__ __forceinline__ void glds16(const void* g, void* l) {
    __builtin_amdgcn_global_load_lds((as1cvp)g, (as3vp)l, 16, 0, 0);
}

// f32->bf16 round-half-up: u + 0x8000, take hi16. Same 0.5-ulp worst case as
// RNE (only exact-tie direction differs -> unbiased for continuous data).
__device__ __forceinline__ u16 f2bf(float f) {
    union { u32 u; float f; } v; v.f = f;
    return (u16)((v.u + 0x8000u) >> 16);
}

// packed f32->2xbf16 half-up: 2 adds + 1 v_perm_b32 (hi16 of each)
__device__ __forceinline__ u32 pk2(float a, float b) {
    union { u32 u; float f; } x, y; x.f = a; y.f = b;
    u32 xr = x.u + 0x8000u, yr = y.u + 0x8000u;
#if __has_builtin(__builtin_amdgcn_perm)
    return __builtin_amdgcn_perm(yr, xr, 0x07060302u);
#else
    return (xr >> 16) | (yr & 0xffff0000u);
#endif
}

// raw v_exp_f32 (= exp2); log2e folded into QSCALE so scores are log2-domain.
__device__ __forceinline__ float ex2(float x) {
#if __has_builtin(__builtin_amdgcn_exp2f)
    return __builtin_amdgcn_exp2f(x);
#else
    float r; asm("v_exp_f32 %0, %1" : "=v"(r) : "v"(x)); return r;
#endif
}

__device__ __forceinline__ float max3f(float a, float b, float c) {
    return fmaxf(fmaxf(a, b), c);   // clang fuses to v_max3_f32
}

// 16x16x16 bf16 MFMA: B-frag layout k=quad*4+j matches C-layout of S^T
__device__ __forceinline__ floatx4 mfma16(bf16x4 a, bf16x4 b, floatx4 c) {
#if __has_builtin(__builtin_amdgcn_mfma_f32_16x16x16bf16_1k)
    return __builtin_amdgcn_mfma_f32_16x16x16bf16_1k(a, b, c, 0, 0, 0);
#else
    asm volatile("v_mfma_f32_16x16x16_bf16 %0, %1, %2, %0" : "+v"(c) : "v"(a), "v"(b));
    return c;
#endif
}

__device__ __forceinline__ uint4 cvt8(const float* __restrict__ p) {
    float4 a = *(const float4*)p;
    float4 b = *(const float4*)(p + 4);
    uint4 q;
    q.x = pk2(a.x, a.y); q.y = pk2(a.z, a.w);
    q.z = pk2(b.x, b.y); q.w = pk2(b.z, b.w);
    return q;
}

// q pre-scale: 1/sqrt(Dh) * log2(e) -> scores are log2-domain, exp via v_exp_f32
#define QSCALE 0.18033688011112042f

// ---------------- convert Q,K,V + 4 weights to bf16 once ----------------
__global__ __launch_bounds__(256) void cvt_all(
    const float* __restrict__ Q, const float* __restrict__ K, const float* __restrict__ V,
    const float* __restrict__ W0, const float* __restrict__ W1,
    const float* __restrict__ W2, const float* __restrict__ W3,
    u16* __restrict__ Qb, u16* __restrict__ Kb, u16* __restrict__ Vb,
    u16* __restrict__ Wb)
{
    const int y = blockIdx.y;
    const float* src; u16* dst;
    if (y == 0)      { src = Q;  dst = Qb; }
    else if (y == 1) { src = K;  dst = Kb; }
    else if (y == 2) { src = V;  dst = Vb; }
    else {
        if (blockIdx.x >= 512) return;
        src = (y == 3) ? W0 : (y == 4) ? W1 : (y == 5) ? W2 : W3;
        dst = Wb + (size_t)(y - 3) * 1048576;
    }
    size_t i = ((size_t)blockIdx.x * 256 + threadIdx.x) * 8;
    *(uint4*)(dst + i) = cvt8(src + i);
}

__global__ __launch_bounds__(256) void cvt_w(
    const float* __restrict__ W0, const float* __restrict__ W1,
    const float* __restrict__ W2, const float* __restrict__ W3,
    u16* __restrict__ out)
{
    const float* src = (blockIdx.y == 0) ? W0 : (blockIdx.y == 1) ? W1
                     : (blockIdx.y == 2) ? W2 : W3;
    size_t i = ((size_t)blockIdx.x * 256 + threadIdx.x) * 8;
    *(uint4*)(out + (size_t)blockIdx.y * 1048576 + i) = cvt8(src + i);
}

// shared epilogue store for QKV projections (z<2: scalar, z=2: vectorized 8B)
__device__ __forceinline__ void qkv_store(
    int z, u16* __restrict__ outp, int rowg, int col, floatx4 a4, float bv, float sc)
{
    union { u32 w[2]; u16 h[4]; u16x4 v4; } pk;
    pk.w[0] = pk2((a4[0] + bv) * sc, (a4[1] + bv) * sc);
    pk.w[1] = pk2((a4[2] + bv) * sc, (a4[3] + bv) * sc);
    int b = rowg >> 11, s = rowg & 2047, h = col >> 6, d = col & 63;
    if (z < 2) {
#pragma unroll
        for (int r = 0; r < 4; r++)
            outp[((size_t)(b * NH + h) * SEQ + s + r) * DH + d] = pk.h[r];
    } else {
        *(u16x4*)(outp + ((size_t)(b * NH + h) * DH + d) * SEQ + s) = pk.v4;
    }
}

// ---------------- QKV projection, both operands bf16, pure glds16 staging ----------------
__global__ __launch_bounds__(256) void gemm_qkv_bb(
    const u16* __restrict__ Qb, const u16* __restrict__ Kb, const u16* __restrict__ Vb,
    const u16* __restrict__ Wb,
    const float* __restrict__ b0, const float* __restrict__ b1, const float* __restrict__ b2,
    u16* __restrict__ qo, u16* __restrict__ ko, u16* __restrict__ vto)
{
    __shared__ __align__(16) u16 As[128 * 32];
    __shared__ __align__(16) u16 Bs[128 * 32];
    const int tid = threadIdx.x, l = tid & 63, w = tid >> 6;
    const int lm = l & 15, quad = l >> 4;
    const int wr = (w >> 1) * 64, wc = (w & 1) * 64;
    const int bm = blockIdx.y * 128, bn = blockIdx.x * 128;
    const int z = blockIdx.z;
    const u16* A      = (z == 0) ? Qb : (z == 1) ? Kb : Vb;
    const u16* W      = Wb + (size_t)z * 1048576;
    const float* bias = (z == 0) ? b0 : (z == 1) ? b1 : b2;

    const int srow = tid >> 2, scol = (tid & 3) * 8;

    floatx4 acc[4][4];
#pragma unroll
    for (int i = 0; i < 4; i++)
#pragma unroll
        for (int j = 0; j < 4; j++) acc[i][j] = (floatx4){0.f, 0.f, 0.f, 0.f};

    for (int kt = 0; kt < DMODEL; kt += 32) {
        __syncthreads();
        glds16(A + (size_t)(bm + srow) * DMODEL + kt + scol, As + w * 512);
        glds16(A + (size_t)(bm + 64 + srow) * DMODEL + kt + scol, As + 2048 + w * 512);
        glds16(W + (size_t)(bn + srow) * DMODEL + kt + scol, Bs + w * 512);
        glds16(W + (size_t)(bn + 64 + srow) * DMODEL + kt + scol, Bs + 2048 + w * 512);
        __syncthreads();

        bf16x8 af[4], bfr[4];
#pragma unroll
        for (int mi = 0; mi < 4; mi++)
            af[mi] = *(const bf16x8*)(As + (wr + mi * 16 + lm) * 32 + quad * 8);
#pragma unroll
        for (int ni = 0; ni < 4; ni++)
            bfr[ni] = *(const bf16x8*)(Bs + (wc + ni * 16 + lm) * 32 + quad * 8);
#pragma unroll
        for (int mi = 0; mi < 4; mi++)
#pragma unroll
            for (int ni = 0; ni < 4; ni++)
                acc[mi][ni] = __builtin_amdgcn_mfma_f32_16x16x32_bf16(
                    af[mi], bfr[ni], acc[mi][ni], 0, 0, 0);
    }

    const float sc = (z == 0) ? QSCALE : 1.0f;
    u16* outp = (z == 0) ? qo : (z == 1) ? ko : vto;
#pragma unroll
    for (int ni = 0; ni < 4; ni++) {
        int col = bn + wc + ni * 16 + lm;
        float bv = bias[col];
#pragma unroll
        for (int mi = 0; mi < 4; mi++)
            qkv_store(z, outp, bm + wr + mi * 16 + quad * 4, col, acc[mi][ni], bv, sc);
    }
}

// ---------------- legacy QKV (A f32 converted in staging) ----------------
template<bool WBF>
__global__ __launch_bounds__(256) void gemm_qkv(
    const float* __restrict__ Qf, const float* __restrict__ Kf, const float* __restrict__ Vf,
    const void* __restrict__ W0, const void* __restrict__ W1, const void* __restrict__ W2,
    const float* __restrict__ b0, const float* __restrict__ b1, const float* __restrict__ b2,
    u16* __restrict__ qo, u16* __restrict__ ko, u16* __restrict__ vto)
{
    __shared__ __align__(16) u16 As[128 * 32];
    __shared__ __align__(16) u16 Bs[128 * 32];
    const int tid = threadIdx.x, l = tid & 63, w = tid >> 6;
    const int lm = l & 15, quad = l >> 4;
    const int wr = (w >> 1) * 64, wc = (w & 1) * 64;
    const int bm = blockIdx.y * 128, bn = blockIdx.x * 128;
    const int z = blockIdx.z;
    const float* A    = (z == 0) ? Qf : (z == 1) ? Kf : Vf;
    const void* Wp    = (z == 0) ? W0 : (z == 1) ? W1 : W2;
    const float* bias = (z == 0) ? b0 : (z == 1) ? b1 : b2;

    floatx4 acc[4][4];
#pragma unroll
    for (int i = 0; i < 4; i++)
#pragma unroll
        for (int j = 0; j < 4; j++) acc[i][j] = (floatx4){0.f, 0.f, 0.f, 0.f};

    for (int kt = 0; kt < DMODEL; kt += 32) {
        __syncthreads();
#pragma unroll
        for (int j = 0; j < 2; j++) {
            int ch = j * 256 + tid, row = ch >> 2, c = ch & 3;
            *(uint4*)(As + ch * 8) = cvt8(A + (size_t)(bm + row) * DMODEL + kt + c * 8);
        }
        if (WBF) {
            const u16* Wb = (const u16*)Wp;
            glds16(Wb + (size_t)(bn + (tid >> 2)) * DMODEL + kt + (tid & 3) * 8, Bs + w * 512);
            glds16(Wb + (size_t)(bn + 64 + (tid >> 2)) * DMODEL + kt + (tid & 3) * 8, Bs + 2048 + w * 512);
        } else {
            const float* Wf = (const float*)Wp;
#pragma unroll
            for (int j = 0; j < 2; j++) {
                int ch = j * 256 + tid, row = ch >> 2, c = ch & 3;
                *(uint4*)(Bs + ch * 8) = cvt8(Wf + (size_t)(bn + row) * DMODEL + kt + c * 8);
            }
        }
        __syncthreads();

        bf16x8 af[4], bfr[4];
#pragma unroll
        for (int mi = 0; mi < 4; mi++)
            af[mi] = *(const bf16x8*)(As + (wr + mi * 16 + lm) * 32 + quad * 8);
#pragma unroll
        for (int ni = 0; ni < 4; ni++)
            bfr[ni] = *(const bf16x8*)(Bs + (wc + ni * 16 + lm) * 32 + quad * 8);
#pragma unroll
        for (int mi = 0; mi < 4; mi++)
#pragma unroll
            for (int ni = 0; ni < 4; ni++)
                acc[mi][ni] = __builtin_amdgcn_mfma_f32_16x16x32_bf16(
                    af[mi], bfr[ni], acc[mi][ni], 0, 0, 0);
    }

    const float sc = (z == 0) ? QSCALE : 1.0f;
    u16* outp = (z == 0) ? qo : (z == 1) ? ko : vto;
#pragma unroll
    for (int ni = 0; ni < 4; ni++) {
        int col = bn + wc + ni * 16 + lm;
        float bv = bias[col];
#pragma unroll
        for (int mi = 0; mi < 4; mi++)
            qkv_store(z, outp, bm + wr + mi * 16 + quad * 4, col, acc[mi][ni], bv, sc);
    }
}

// ---------------- O-projection: A bf16, W bf16/f32, out f32. 128x64 tiles ----------------
template<bool WBF>
__global__ __launch_bounds__(256) void gemm_o(
    const u16* __restrict__ A, const void* __restrict__ Wp,
    const float* __restrict__ bias, float* __restrict__ out)
{
    __shared__ __align__(16) u16 As[128 * 32];
    __shared__ __align__(16) u16 Bs[64 * 32];
    const int tid = threadIdx.x, l = tid & 63, w = tid >> 6;
    const int lm = l & 15, quad = l >> 4;
    const int bm = blockIdx.y * 128, bn = blockIdx.x * 64;

    floatx4 acc[2][4];
#pragma unroll
    for (int i = 0; i < 2; i++)
#pragma unroll
        for (int j = 0; j < 4; j++) acc[i][j] = (floatx4){0.f, 0.f, 0.f, 0.f};

    for (int kt = 0; kt < DMODEL; kt += 32) {
        __syncthreads();
        glds16(A + (size_t)(bm + (tid >> 2)) * DMODEL + kt + (tid & 3) * 8, As + w * 512);
        glds16(A + (size_t)(bm + 64 + (tid >> 2)) * DMODEL + kt + (tid & 3) * 8, As + 2048 + w * 512);
        if (WBF) {
            glds16((const u16*)Wp + (size_t)(bn + (tid >> 2)) * DMODEL + kt + (tid & 3) * 8, Bs + w * 512);
        } else {
            *(uint4*)(Bs + tid * 8) =
                cvt8((const float*)Wp + (size_t)(bn + (tid >> 2)) * DMODEL + kt + (tid & 3) * 8);
        }
        __syncthreads();

        bf16x8 af[2], bfr[4];
#pragma unroll
        for (int mi = 0; mi < 2; mi++)
            af[mi] = *(const bf16x8*)(As + (w * 32 + mi * 16 + lm) * 32 + quad * 8);
#pragma unroll
        for (int ni = 0; ni < 4; ni++)
            bfr[ni] = *(const bf16x8*)(Bs + (ni * 16 + lm) * 32 + quad * 8);
#pragma unroll
        for (int mi = 0; mi < 2; mi++)
#pragma unroll
            for (int ni = 0; ni < 4; ni++)
                acc[mi][ni] = __builtin_amdgcn_mfma_f32_16x16x32_bf16(
                    af[mi], bfr[ni], acc[mi][ni], 0, 0, 0);
    }

#pragma unroll
    for (int ni = 0; ni < 4; ni++) {
        int col = bn + ni * 16 + lm;
        float bv = bias[col];
#pragma unroll
        for (int mi = 0; mi < 2; mi++) {
#pragma unroll
            for (int r = 0; r < 4; r++) {
                int rowg = bm + w * 32 + mi * 16 + quad * 4 + r;
                out[(size_t)rowg * DMODEL + col] = acc[mi][ni][r] + bv;
            }
        }
    }
}

// ---------------- Flash attention v8: in-block KV-split ----------------
// grid (SEQ/128, B*NH), 512 threads / 8 waves. Wave w: q-rows (w&3)*32..+31
// (2 n-tiles), KEY HALF w>>2 (0: keys 0..1023, 1: keys 1024..2047).
// Rationale (r2 counters): LDS data pipe ~70% occupied; every wave re-reads
// the K/V tile, so reads scale with wave count. 32 rows/wave halves per-wave
// read traffic vs v7 while in-block split keeps 16 waves/CU. 16 staging
// rounds stage BOTH halves' tiles (36.8KB LDS, 2 blocks/CU).
// S^T = K*Q^T; scores log2-domain (QSCALE); defer-max THR=8; l via ones-MFMA.
// Halves merge in-block through LDS (f32) at the end: O = (OA*eA + OB*eB)/l.
#define SP 72
__global__ __launch_bounds__(512, 4) void attn_kernel(
    const u16* __restrict__ q, const u16* __restrict__ k,
    const u16* __restrict__ vt, u16* __restrict__ out)
{
    // [K half0][K half1][V half0][V half1], each 64*SP u16 = 9216B; total 36864B
    __shared__ __align__(16) u16 smem[4 * 64 * SP];
    const int tid = threadIdx.x, l = tid & 63, w = tid >> 6;   // w in 0..7
    const int lm = l & 15, quad = l >> 4;
    const int qt = blockIdx.x, bh = blockIdx.y;
    const int b = bh >> 4, h = bh & 15;
    const int rg = w & 3, half = w >> 2;

    const u16* Kh = smem + half * (64 * SP);
    const u16* Vh = smem + (2 + half) * (64 * SP);

    bf16x8 qf[2][2];
#pragma unroll
    for (int nt = 0; nt < 2; nt++) {
        int row = qt * 128 + rg * 32 + nt * 16 + lm;
        const u16* qp = q + ((size_t)bh * SEQ + row) * DH;
        qf[nt][0] = *(const bf16x8*)(qp + quad * 8);
        qf[nt][1] = *(const bf16x8*)(qp + 32 + quad * 8);
    }

    floatx4 O[4][2];
#pragma unroll
    for (int dt = 0; dt < 4; dt++)
#pragma unroll
        for (int nt = 0; nt < 2; nt++) O[dt][nt] = (floatx4){0.f, 0.f, 0.f, 0.f};
    floatx4 Ol[2] = {(floatx4){0.f,0.f,0.f,0.f}, (floatx4){0.f,0.f,0.f,0.f}};
    float mrun[2] = {-1e30f, -1e30f};

    const bf16x4 onesb = {(short)0x3F80, (short)0x3F80, (short)0x3F80, (short)0x3F80};

    const int srow = tid >> 3, scol = (tid & 7) * 8;  // srow 0..63, scol 0..56
    // permuted V position base: chunk scol..scol+3 -> pb0, scol+4..scol+7 -> pb0+16
    const int pb0 = ((scol >> 2) & 3) * 16 + (scol >> 4) * 4;
    const u16* kbase = k + (size_t)bh * SEQ * DH;
    const u16* vbase = vt + (size_t)bh * DH * SEQ;
    // half B offsets: +1024 keys
    uint4 krA = *(const uint4*)(kbase + (size_t)srow * DH + scol);
    uint4 krB = *(const uint4*)(kbase + (size_t)(1024 + srow) * DH + scol);
    uint4 vrA = *(const uint4*)(vbase + (size_t)srow * SEQ + scol);
    uint4 vrB = *(const uint4*)(vbase + (size_t)srow * SEQ + 1024 + scol);

    u16* K0 = smem;
    u16* K1 = smem + 64 * SP;
    u16* V0 = smem + 2 * (64 * SP);
    u16* V1 = smem + 3 * (64 * SP);

    for (int t = 0; t < 16; t++) {
        __syncthreads();
        *(uint4*)(K0 + srow * SP + scol) = krA;
        *(uint4*)(K1 + srow * SP + scol) = krB;
        *(uint2*)(V0 + srow * SP + pb0)      = make_uint2(vrA.x, vrA.y);
        *(uint2*)(V0 + srow * SP + pb0 + 16) = make_uint2(vrA.z, vrA.w);
        *(uint2*)(V1 + srow * SP + pb0)      = make_uint2(vrB.x, vrB.y);
        *(uint2*)(V1 + srow * SP + pb0 + 16) = make_uint2(vrB.z, vrB.w);
        __syncthreads();
        if (t + 1 < 16) {
            const u16* kg = kbase + (size_t)(t + 1) * 64 * DH;
            const u16* vg = vbase + (size_t)(t + 1) * 64;
            krA = *(const uint4*)(kg + (size_t)srow * DH + scol);
            krB = *(const uint4*)(kg + (size_t)(1024 + srow) * DH + scol);
            vrA = *(const uint4*)(vg + (size_t)srow * SEQ + scol);
            vrB = *(const uint4*)(vg + (size_t)srow * SEQ + 1024 + scol);
        }

        // S^T = K·Q^T (K-frag reads shared across both n-tiles)
        floatx4 Sc[4][2];
        __builtin_amdgcn_s_setprio(1);
#pragma unroll
        for (int mt = 0; mt < 4; mt++) {
            bf16x8 ka0 = *(const bf16x8*)(Kh + (mt * 16 + lm) * SP + quad * 8);
            bf16x8 ka1 = *(const bf16x8*)(Kh + (mt * 16 + lm) * SP + 32 + quad * 8);
#pragma unroll
            for (int nt = 0; nt < 2; nt++) {
                floatx4 c = (floatx4){0.f, 0.f, 0.f, 0.f};
                c = __builtin_amdgcn_mfma_f32_16x16x32_bf16(ka0, qf[nt][0], c, 0, 0, 0);
                c = __builtin_amdgcn_mfma_f32_16x16x32_bf16(ka1, qf[nt][1], c, 0, 0, 0);
                Sc[mt][nt] = c;
            }
        }
        __builtin_amdgcn_s_setprio(0);

        // online softmax per n-tile: per-lane rows, log2 domain, defer-max
        bf16x4 pb[4][2];
#pragma unroll
        for (int nt = 0; nt < 2; nt++) {
            float m0 = max3f(Sc[0][nt][0], Sc[0][nt][1], Sc[0][nt][2]);
            float m1 = max3f(Sc[0][nt][3], Sc[1][nt][0], Sc[1][nt][1]);
            float m2 = max3f(Sc[1][nt][2], Sc[1][nt][3], Sc[2][nt][0]);
            float m3 = max3f(Sc[2][nt][1], Sc[2][nt][2], Sc[2][nt][3]);
            float m4 = max3f(Sc[3][nt][0], Sc[3][nt][1], Sc[3][nt][2]);
            m0 = max3f(m0, m1, m2);
            m0 = max3f(m0, m3, m4);
            m0 = fmaxf(m0, Sc[3][nt][3]);
            m0 = fmaxf(m0, __shfl_xor(m0, 16));
            m0 = fmaxf(m0, __shfl_xor(m0, 32));

            if (!__all(m0 <= mrun[nt] + 8.0f)) {
                float mn = fmaxf(mrun[nt], m0);
                float alpha = ex2(mrun[nt] - mn);
                mrun[nt] = mn;
#pragma unroll
                for (int dt = 0; dt < 4; dt++)
#pragma unroll
                    for (int r = 0; r < 4; r++) O[dt][nt][r] *= alpha;
                Ol[nt][0] *= alpha;   // only element 0 is ever read
            }
            const float mn = mrun[nt];
#pragma unroll
            for (int mt = 0; mt < 4; mt++) {
#pragma unroll
                for (int r = 0; r < 4; r++) Sc[mt][nt][r] = ex2(Sc[mt][nt][r] - mn);
                union { u32 w2[2]; bf16x4 v; } pku;
                pku.w2[0] = pk2(Sc[mt][nt][0], Sc[mt][nt][1]);
                pku.w2[1] = pk2(Sc[mt][nt][2], Sc[mt][nt][3]);
                pb[mt][nt] = pku.v;
            }
        }

        __builtin_amdgcn_s_setprio(1);
        // l += colsum(P) via all-ones A-frag
#pragma unroll
        for (int nt = 0; nt < 2; nt++) {
            Ol[nt] = mfma16(onesb, pb[0][nt], Ol[nt]);
            Ol[nt] = mfma16(onesb, pb[1][nt], Ol[nt]);
            Ol[nt] = mfma16(onesb, pb[2][nt], Ol[nt]);
            Ol[nt] = mfma16(onesb, pb[3][nt], Ol[nt]);
        }

        // O^T += V^T·P^T : V-frag reads shared across both n-tiles
#pragma unroll
        for (int dt = 0; dt < 4; dt++) {
            const u16* vp = Vh + (dt * 16 + lm) * SP + quad * 16;
            bf16x8 v8a = *(const bf16x8*)vp;        // mt 0 (elems 0-3), mt 1 (4-7)
            bf16x8 v8b = *(const bf16x8*)(vp + 8);  // mt 2, mt 3
            bf16x4 va0 = __builtin_shufflevector(v8a, v8a, 0, 1, 2, 3);
            bf16x4 va1 = __builtin_shufflevector(v8a, v8a, 4, 5, 6, 7);
            bf16x4 va2 = __builtin_shufflevector(v8b, v8b, 0, 1, 2, 3);
            bf16x4 va3 = __builtin_shufflevector(v8b, v8b, 4, 5, 6, 7);
            O[dt][0] = mfma16(va0, pb[0][0], O[dt][0]);
            O[dt][1] = mfma16(va0, pb[0][1], O[dt][1]);
            O[dt][0] = mfma16(va1, pb[1][0], O[dt][0]);
            O[dt][1] = mfma16(va1, pb[1][1], O[dt][1]);
            O[dt][0] = mfma16(va2, pb[2][0], O[dt][0]);
            O[dt][1] = mfma16(va2, pb[2][1], O[dt][1]);
            O[dt][0] = mfma16(va3, pb[3][0], O[dt][0]);
            O[dt][1] = mfma16(va3, pb[3][1], O[dt][1]);
        }
        __builtin_amdgcn_s_setprio(0);
    }

    // ---- in-block merge of the two key-halves through LDS (f32) ----
    __syncthreads();
    float* obuf  = (float*)smem;           // [4 rg][64 lane][2 nt][16] = 32768B
    float* mlbuf = (float*)smem + 8192;    // [4 rg][64 lane][2 nt][2]  =  4096B
    if (w >= 4) {
#pragma unroll
        for (int nt = 0; nt < 2; nt++) {
            float* ob = obuf + (((rg * 64 + l) * 2 + nt) << 4);
#pragma unroll
            for (int dt = 0; dt < 4; dt++)
                *(floatx4*)(ob + dt * 4) = O[dt][nt];
            *(float2*)(mlbuf + ((rg * 64 + l) * 2 + nt) * 2) =
                make_float2(mrun[nt], Ol[nt][0]);
        }
    }
    __syncthreads();
    if (w < 4) {
#pragma unroll
        for (int nt = 0; nt < 2; nt++) {
            float* ob = obuf + (((rg * 64 + l) * 2 + nt) << 4);
            float2 ml = *(float2*)(mlbuf + ((rg * 64 + l) * 2 + nt) * 2);
            float mA = mrun[nt], lA = Ol[nt][0];
            float mB = ml.x, lB = ml.y;
            float mm = fmaxf(mA, mB);
            float eA = ex2(mA - mm), eB = ex2(mB - mm);
            float inv = 1.0f / (lA * eA + lB * eB);
            float wA = eA * inv, wB = eB * inv;
            int s = qt * 128 + rg * 32 + nt * 16 + lm;
            u16* op = out + ((size_t)b * SEQ + s) * DMODEL + h * DH;
#pragma unroll
            for (int dt = 0; dt < 4; dt++) {
                floatx4 Ob = *(const floatx4*)(ob + dt * 4);
                union { u32 w2[2]; u16x4 v; } pku;
                pku.w2[0] = pk2(O[dt][nt][0] * wA + Ob[0] * wB,
                                O[dt][nt][1] * wA + Ob[1] * wB);
                pku.w2[1] = pk2(O[dt][nt][2] * wA + Ob[2] * wB,
                                O[dt][nt][3] * wA + Ob[3] * wB);
                *(u16x4*)(op + dt * 16 + quad * 4) = pku.v;
            }
        }
    }
}

extern "C" void kernel_launch(void* const* d_in, const int* in_sizes, int n_in,
                              void* d_out, int out_size, void* d_ws, size_t ws_size,
                              hipStream_t stream) {
    (void)in_sizes; (void)n_in; (void)out_size;
    const float* Q  = (const float*)d_in[0];
    const float* K  = (const float*)d_in[1];
    const float* V  = (const float*)d_in[2];
    const float* Wq = (const float*)d_in[3];
    const float* bq = (const float*)d_in[4];
    const float* Wk = (const float*)d_in[5];
    const float* bk = (const float*)d_in[6];
    const float* Wv = (const float*)d_in[7];
    const float* bv = (const float*)d_in[8];
    const float* Wo = (const float*)d_in[9];
    const float* bo = (const float*)d_in[10];

    const size_t NEL = (size_t)2 * NH * SEQ * DH;  // 4,194,304 elements
    u16* base = (u16*)d_ws;
    dim3 bb(256);
    dim3 ab(512);

    if (ws_size >= 8 * NEL * 2) {
        u16* Qb   = base;
        u16* Kb   = Qb + NEL;
        u16* Vb   = Kb + NEL;
        u16* Wb   = Vb + NEL;
        u16* qws  = Wb + NEL;
        u16* kws  = qws + NEL;
        u16* vtws = kws + NEL;
        u16* aws  = vtws + NEL;
        cvt_all<<<dim3(2048, 7), bb, 0, stream>>>(Q, K, V, Wq, Wk, Wv, Wo, Qb, Kb, Vb, Wb);
        gemm_qkv_bb<<<dim3(8, 32, 3), bb, 0, stream>>>(
            Qb, Kb, Vb, Wb, bq, bk, bv, qws, kws, vtws);
        attn_kernel<<<dim3(SEQ / 128, 2 * NH), ab, 0, stream>>>(qws, kws, vtws, aws);
        gemm_o<true><<<dim3(16, 32), bb, 0, stream>>>(aws, Wb + 3145728, bo, (float*)d_out);
    } else if (ws_size >= 5 * NEL * 2) {
        u16* Wb = base;
        u16* qws = base + NEL; u16* kws = qws + NEL; u16* vtws = kws + NEL; u16* aws = vtws + NEL;
        cvt_w<<<dim3(512, 4), bb, 0, stream>>>(Wq, Wk, Wv, Wo, Wb);
        gemm_qkv<true><<<dim3(8, 32, 3), bb, 0, stream>>>(
            Q, K, V, Wb, Wb + 1048576, Wb + 2097152, bq, bk, bv, qws, kws, vtws);
        attn_kernel<<<dim3(SEQ / 128, 2 * NH), ab, 0, stream>>>(qws, kws, vtws, aws);
        gemm_o<true><<<dim3(16, 32), bb, 0, stream>>>(aws, Wb + 3145728, bo, (float*)d_out);
    } else {
        u16* qws = base; u16* kws = qws + NEL; u16* vtws = kws + NEL; u16* aws = vtws + NEL;
        gemm_qkv<false><<<dim3(8, 32, 3), bb, 0, stream>>>(
            Q, K, V, Wq, Wk, Wv, bq, bk, bv, qws, kws, vtws);
        attn_kernel<<<dim3(SEQ / 128, 2 * NH), ab, 0, stream>>>(qws, kws, vtws, aws);
        gemm_o<false><<<dim3(16, 32), bb, 0, stream>>>(aws, Wo, bo, (float*)d_out);
    }
}